// Round 1
// baseline (6111.719 us; speedup 1.0000x reference)
//
#include <hip/hip_runtime.h>

#define B_ 128
#define T_ 512
#define E_ 256
#define H_ 512
#define NSLICE 16   // h-slices per (dir, bgroup)
#define NBG 4       // batch groups of 32 rows
#define AGENT __HIP_MEMORY_SCOPE_AGENT

typedef float f32x16 __attribute__((ext_vector_type(16)));
typedef unsigned short u16x8 __attribute__((ext_vector_type(8)));
typedef __bf16 bf16x8 __attribute__((ext_vector_type(8)));

union U8 { u16x8 u; bf16x8 b; };

__device__ __forceinline__ unsigned short f2bf(float f) {
    unsigned u = __float_as_uint(f);
    return (unsigned short)((u + 0x7FFFu + ((u >> 16) & 1u)) >> 16);
}
__device__ __forceinline__ float bf2f(unsigned short s) {
    return __uint_as_float(((unsigned)s) << 16);
}
__device__ __forceinline__ float sigm(float x) { return 1.f / (1.f + __expf(-x)); }
__device__ __forceinline__ float tanh_f(float x) {
    float e = __expf(2.f * x);
    return 1.f - 2.f / (e + 1.f);   // inf-safe at both ends
}

// ---------------- gather: x_bf16[b][t][e] = bf16(emb[inputs[b][t]][e]) --------
__global__ void gather_k(const int* __restrict__ idx, const float* __restrict__ emb,
                         unsigned short* __restrict__ x) {
    int row = blockIdx.x;          // b*T + t
    int e = threadIdx.x;           // 0..255
    int id = idx[row];
    x[row * E_ + e] = f2bf(emb[id * E_ + e]);
}

// ---------------- persistent bidirectional GRU ----------------
// grid: 128 WGs = dir(2) x bgroup(4) x slice(16); 192 threads = 3 waves (r,z,n)
__global__ __launch_bounds__(192, 1) void gru_k(
    const unsigned short* __restrict__ x,
    const float* __restrict__ Wih_f, const float* __restrict__ Whh_f,
    const float* __restrict__ bih_f, const float* __restrict__ bhh_f,
    const float* __restrict__ Wih_b, const float* __restrict__ Whh_b,
    const float* __restrict__ bih_b, const float* __restrict__ bhh_b,
    unsigned short* __restrict__ hbuf,   // [2 dirs][2 bufs][128][512] bf16
    unsigned int* __restrict__ cnt)      // [2][4][T+1]
{
    const int wg  = blockIdx.x;
    const int dir = wg >> 6;          // 0 fwd, 1 bwd
    const int bg  = (wg >> 4) & 3;
    const int sl  = wg & 15;
    const int wid = threadIdx.x >> 6;   // 0=r 1=z 2=n
    const int lane = threadIdx.x & 63;
    const int l31 = lane & 31;
    const int lh  = lane >> 5;          // 0/1

    const float* Wih = dir ? Wih_b : Wih_f;
    const float* Whh = dir ? Whh_b : Whh_f;
    const float* bih = dir ? bih_b : bih_f;
    const float* bhh = dir ? bhh_b : bhh_f;

    // W row this lane serves (B-operand col): gate block + slice + lane col
    const int gcol = wid * H_ + sl * 32 + l31;

    // ---- load persistent B-fragments: 48 x (16B/lane) = 192 VGPRs ----
    U8 Bf[48];
#pragma unroll
    for (int c = 0; c < 16; ++c) {               // x-part K=0..255
        const float* p = Wih + gcol * E_ + c * 16 + 8 * lh;
        float4 a = *(const float4*)p;
        float4 b = *(const float4*)(p + 4);
        U8 v;
        v.u[0] = f2bf(a.x); v.u[1] = f2bf(a.y); v.u[2] = f2bf(a.z); v.u[3] = f2bf(a.w);
        v.u[4] = f2bf(b.x); v.u[5] = f2bf(b.y); v.u[6] = f2bf(b.z); v.u[7] = f2bf(b.w);
        Bf[c] = v;
    }
#pragma unroll
    for (int c = 0; c < 32; ++c) {               // h-part K=256..767
        const float* p = Whh + gcol * H_ + c * 16 + 8 * lh;
        float4 a = *(const float4*)p;
        float4 b = *(const float4*)(p + 4);
        U8 v;
        v.u[0] = f2bf(a.x); v.u[1] = f2bf(a.y); v.u[2] = f2bf(a.z); v.u[3] = f2bf(a.w);
        v.u[4] = f2bf(b.x); v.u[5] = f2bf(b.y); v.u[6] = f2bf(b.z); v.u[7] = f2bf(b.w);
        Bf[16 + c] = v;
    }

    const float bi = bih[gcol];
    const float bh = bhh[gcol];

    const int b = bg * 32 + l31;                 // A-operand row (batch)
    const unsigned short* xrow = x + (b * T_) * E_;
    unsigned short* hb = hbuf + dir * (2 * B_ * H_);
    unsigned int* cn = cnt + (dir * NBG + bg) * (T_ + 1);

    __shared__ float lds_r[2][16][64];
    __shared__ float lds_z[2][16][64];

    f32x16 hold;                                 // n-wave: own h slice, f32
#pragma unroll
    for (int i = 0; i < 16; ++i) hold[i] = 0.f;

    for (int t = 0; t < T_; ++t) {
        const int tx = dir ? (T_ - 1 - t) : t;
        const int p = t & 1;

        f32x16 acc, acc2;                        // acc: x-part (+b_ih), acc2: h-part (+b_hh)
#pragma unroll
        for (int i = 0; i < 16; ++i) { acc[i] = bi; acc2[i] = bh; }

        // x-part: independent of sync — issue & compute first
        {
            const unsigned short* xp = xrow + tx * E_;
            U8 ax[16];
#pragma unroll
            for (int c = 0; c < 16; ++c) ax[c].u = *(const u16x8*)(xp + c * 16 + 8 * lh);
#pragma unroll
            for (int c = 0; c < 16; ++c)
                acc = __builtin_amdgcn_mfma_f32_32x32x16_bf16(ax[c].b, Bf[c].b, acc, 0, 0, 0);
        }

        if (t > 0) {
            // wait for all 16 slice-producers of previous step
            while (__hip_atomic_load(cn + t, __ATOMIC_RELAXED, AGENT) < NSLICE)
                __builtin_amdgcn_s_sleep(2);
            (void)__hip_atomic_load(cn + t, __ATOMIC_ACQUIRE, AGENT);

            const unsigned short* hp = hb + ((t & 1) * B_ + b) * H_;
            U8 ah[32];
#pragma unroll
            for (int c = 0; c < 32; ++c) ah[c].u = *(const u16x8*)(hp + c * 16 + 8 * lh);
#pragma unroll
            for (int c = 0; c < 32; ++c)
                acc2 = __builtin_amdgcn_mfma_f32_32x32x16_bf16(ah[c].b, Bf[16 + c].b, acc2, 0, 0, 0);
        }

        // gates: r,z waves publish to LDS; n wave does the update
        if (wid == 0) {
#pragma unroll
            for (int i = 0; i < 16; ++i) lds_r[p][i][lane] = sigm(acc[i] + acc2[i]);
        } else if (wid == 1) {
#pragma unroll
            for (int i = 0; i < 16; ++i) lds_z[p][i][lane] = sigm(acc[i] + acc2[i]);
        }
        __syncthreads();
        if (wid == 2) {
            unsigned short* hw = hb + (((t + 1) & 1) * B_) * H_;
#pragma unroll
            for (int i = 0; i < 16; ++i) {
                float r = lds_r[p][i][lane];
                float z = lds_z[p][i][lane];
                float n = tanh_f(acc[i] + r * acc2[i]);   // xn + r*(hn+b_hh_n)
                float hn = (1.f - z) * n + z * hold[i];
                hold[i] = hn;
                int row = bg * 32 + (i & 3) + 8 * (i >> 2) + 4 * lh;  // C/D row map
                hw[row * H_ + sl * 32 + l31] = f2bf(hn);
            }
            if (lane == 0)
                __hip_atomic_fetch_add(cn + t + 1, 1u, __ATOMIC_RELEASE, AGENT);
        }
    }
}

// ---------------- FC head: out[b] = sigmoid(concat(h_f,h_b) . fc_w + fc_b) ----
__global__ void fc_k(const unsigned short* __restrict__ hbuf,
                     const float* __restrict__ fcw, const float* __restrict__ fcb,
                     float* __restrict__ out) {
    int bb = blockIdx.x;
    int l = threadIdx.x;       // 64 threads = 1 wave
    float s = 0.f;
    for (int j = l; j < H_; j += 64) {
        s += bf2f(hbuf[bb * H_ + j]) * fcw[j];                       // fwd, buf 0
        s += bf2f(hbuf[2 * B_ * H_ + bb * H_ + j]) * fcw[H_ + j];    // bwd, buf 0
    }
#pragma unroll
    for (int o = 32; o > 0; o >>= 1) s += __shfl_down(s, o);
    if (l == 0) out[bb] = sigm(s + fcb[0]);
}

extern "C" void kernel_launch(void* const* d_in, const int* in_sizes, int n_in,
                              void* d_out, int out_size, void* d_ws, size_t ws_size,
                              hipStream_t stream) {
    (void)in_sizes; (void)n_in; (void)out_size; (void)ws_size;
    const int*   inputs = (const int*)d_in[0];
    const float* emb    = (const float*)d_in[1];
    const float* Wih_f  = (const float*)d_in[2];
    const float* Whh_f  = (const float*)d_in[3];
    const float* bih_f  = (const float*)d_in[4];
    const float* bhh_f  = (const float*)d_in[5];
    const float* Wih_b  = (const float*)d_in[6];
    const float* Whh_b  = (const float*)d_in[7];
    const float* bih_b  = (const float*)d_in[8];
    const float* bhh_b  = (const float*)d_in[9];
    const float* fcw    = (const float*)d_in[10];
    const float* fcb    = (const float*)d_in[11];
    float* out = (float*)d_out;

    char* w = (char*)d_ws;
    unsigned short* xbuf = (unsigned short*)w;                          // 33,554,432 B
    unsigned short* hbuf = (unsigned short*)(w + 33554432);             //    524,288 B
    unsigned int*   cnt  = (unsigned int*)(w + 33554432 + 524288);      //     16,416 B

    hipMemsetAsync(cnt, 0, 2 * NBG * (T_ + 1) * sizeof(unsigned int), stream);
    gather_k<<<B_ * T_, E_, 0, stream>>>(inputs, emb, xbuf);
    gru_k<<<128, 192, 0, stream>>>(xbuf, Wih_f, Whh_f, bih_f, bhh_f,
                                   Wih_b, Whh_b, bih_b, bhh_b, hbuf, cnt);
    fc_k<<<B_, 64, 0, stream>>>(hbuf, fcw, fcb, out);
}